// Round 3
// baseline (527.938 us; speedup 1.0000x reference)
//
#include <hip/hip_runtime.h>
#include <hip/hip_bf16.h>

#define NLEV 16
#define TSIZE (1u << 19)
#define TMASK ((1u << 19) - 1u)
#define P1 2654435761u
#define P2 805459861u

typedef float v2f __attribute__((ext_vector_type(2)));

// packed fp32 fma: acc.xy += a.xy * w.xy, weight pair in SGPRs (uniform)
__device__ __forceinline__ void pk_fma_vs(v2f& acc, v2f a, v2f w) {
    asm("v_pk_fma_f32 %0, %1, %2, %0" : "+v"(acc) : "v"(a), "s"(w));
}

// floor(16 * b^l), b = 256^(1/15) — matches numpy float64 computation.
__device__ __constant__ float c_res[NLEV] = {
    16.f, 23.f, 33.f, 48.f, 70.f, 101.f, 147.f, 212.f,
    307.f, 445.f, 645.f, 933.f, 1351.f, 1955.f, 2830.f, 4096.f};

// ---------------- Phase 1: hash encode, thread per (point, level) ----------
// 1-D grid with XCD-pinned levels: block b -> xcd slot b%8; each XCD runs its
// two levels (slot, slot+8) SEQUENTIALLY so the active level's 4 MB table is
// resident in that XCD's 4 MB L2. Perf heuristic only — correctness does not
// depend on the dispatch mapping.
__global__ __launch_bounds__(256) void hash_encode_kernel(
    const float* __restrict__ pos,      // [N,3]
    const float* __restrict__ table,    // [16, 2^19, 2]
    __hip_bfloat162* __restrict__ feat, // [16][N] level-major
    int n, unsigned bpl)                // bpl = blocks per level
{
    unsigned b = blockIdx.x;
    unsigned slot = b & 7u;
    unsigned jj = b >> 3u;
    unsigned l = slot + 8u * (jj / bpl);
    unsigned pblk = jj % bpl;
    int i = (int)(pblk * 256u + threadIdx.x);
    if (i >= n) return;

    float x = (pos[3 * i + 0] + 1.f) * 0.5f;
    float y = (pos[3 * i + 1] + 1.f) * 0.5f;
    float z = (pos[3 * i + 2] + 1.f) * 0.5f;

    float r = c_res[l];
    float sx = x * r, sy = y * r, sz = z * r;
    float fx = floorf(sx), fy = floorf(sy), fz = floorf(sz);
    float wx = sx - fx, wy = sy - fy, wz = sz - fz;
    unsigned ix = (unsigned)fx, iy = (unsigned)fy, iz = (unsigned)fz;
    unsigned hy0 = iy * P1, hy1 = hy0 + P1;
    unsigned hz0 = iz * P2, hz1 = hz0 + P2;
    unsigned a00 = hy0 ^ hz0, a10 = hy1 ^ hz0;
    unsigned a01 = hy0 ^ hz1, a11 = hy1 ^ hz1;
    unsigned ix1 = ix + 1u;

    const float2* tl = (const float2*)table + (size_t)l * TSIZE;
    // 8 independent gathers, all issued before any use
    float2 e000 = tl[(ix  ^ a00) & TMASK];
    float2 e100 = tl[(ix1 ^ a00) & TMASK];
    float2 e010 = tl[(ix  ^ a10) & TMASK];
    float2 e110 = tl[(ix1 ^ a10) & TMASK];
    float2 e001 = tl[(ix  ^ a01) & TMASK];
    float2 e101 = tl[(ix1 ^ a01) & TMASK];
    float2 e011 = tl[(ix  ^ a11) & TMASK];
    float2 e111 = tl[(ix1 ^ a11) & TMASK];

    float ux = 1.f - wx, uy = 1.f - wy, uz = 1.f - wz;
    float w000 = ux * uy * uz, w100 = wx * uy * uz;
    float w010 = ux * wy * uz, w110 = wx * wy * uz;
    float w001 = ux * uy * wz, w101 = wx * uy * wz;
    float w011 = ux * wy * wz, w111 = wx * wy * wz;

    float f0 = e000.x * w000 + e100.x * w100 + e010.x * w010 + e110.x * w110 +
               e001.x * w001 + e101.x * w101 + e011.x * w011 + e111.x * w111;
    float f1 = e000.y * w000 + e100.y * w100 + e010.y * w010 + e110.y * w110 +
               e001.y * w001 + e101.y * w101 + e011.y * w011 + e111.y * w111;

    __hip_bfloat162 v;
    v.x = __float2bfloat16(f0);
    v.y = __float2bfloat16(f1);
    feat[(size_t)l * n + i] = v;
}

// ---------------- Phase 2: packed fp32 MLP, thread per point ---------------
__global__ __launch_bounds__(256) void mlp_kernel(
    const float* __restrict__ pos,
    const __hip_bfloat162* __restrict__ feat,  // [16][N]
    const float* __restrict__ W0,      // [32,64]
    const float* __restrict__ W1,      // [64,64]
    const float* __restrict__ W2,      // [64,64]
    const float* __restrict__ W3,      // [64,4]
    float* __restrict__ out,           // rgb [N,3] then density [N]
    int n)
{
    int id = blockIdx.x * 256 + threadIdx.x;
    int i = id < n ? id : n - 1;   // no early return: keep weight loads uniform

    float x = (pos[3 * i + 0] + 1.f) * 0.5f;
    float y = (pos[3 * i + 1] + 1.f) * 0.5f;
    float z = (pos[3 * i + 2] + 1.f) * 0.5f;
    bool sel = (x > 0.f) && (x < 1.f) && (y > 0.f) && (y < 1.f) &&
               (z > 0.f) && (z < 1.f);

    v2f h0[32];
#pragma unroll
    for (int p = 0; p < 32; ++p) h0[p] = (v2f){0.f, 0.f};

#pragma unroll
    for (int l = 0; l < NLEV; ++l) {
        __hip_bfloat162 v = feat[(size_t)l * n + i];
        float f0 = __bfloat162float(v.x);
        float f1 = __bfloat162float(v.y);
        v2f f00 = (v2f){f0, f0};
        v2f f11 = (v2f){f1, f1};
        const v2f* wa = (const v2f*)(W0 + (2 * l) * 64);
        const v2f* wb = (const v2f*)(W0 + (2 * l + 1) * 64);
#pragma unroll
        for (int p = 0; p < 32; ++p) {
            pk_fma_vs(h0[p], f11, wb[p]);
            pk_fma_vs(h0[p], f00, wa[p]);
        }
    }
#pragma unroll
    for (int p = 0; p < 32; ++p) {
        h0[p].x = fmaxf(h0[p].x, 0.f);
        h0[p].y = fmaxf(h0[p].y, 0.f);
    }

    v2f h1[32];
#pragma unroll
    for (int p = 0; p < 32; ++p) h1[p] = (v2f){0.f, 0.f};
#pragma unroll
    for (int k = 0; k < 64; ++k) {
        float v = (k & 1) ? h0[k >> 1].y : h0[k >> 1].x;
        v2f vv = (v2f){v, v};
        const v2f* wr = (const v2f*)(W1 + k * 64);
#pragma unroll
        for (int p = 0; p < 32; ++p) pk_fma_vs(h1[p], vv, wr[p]);
    }
#pragma unroll
    for (int p = 0; p < 32; ++p) {
        h1[p].x = fmaxf(h1[p].x, 0.f);
        h1[p].y = fmaxf(h1[p].y, 0.f);
    }

#pragma unroll
    for (int p = 0; p < 32; ++p) h0[p] = (v2f){0.f, 0.f};
#pragma unroll
    for (int k = 0; k < 64; ++k) {
        float v = (k & 1) ? h1[k >> 1].y : h1[k >> 1].x;
        v2f vv = (v2f){v, v};
        const v2f* wr = (const v2f*)(W2 + k * 64);
#pragma unroll
        for (int p = 0; p < 32; ++p) pk_fma_vs(h0[p], vv, wr[p]);
    }
#pragma unroll
    for (int p = 0; p < 32; ++p) {
        h0[p].x = fmaxf(h0[p].x, 0.f);
        h0[p].y = fmaxf(h0[p].y, 0.f);
    }

    v2f o01 = (v2f){0.f, 0.f}, o23 = (v2f){0.f, 0.f};
#pragma unroll
    for (int k = 0; k < 64; ++k) {
        float v = (k & 1) ? h0[k >> 1].y : h0[k >> 1].x;
        v2f vv = (v2f){v, v};
        const v2f* wr = (const v2f*)(W3 + k * 4);
        pk_fma_vs(o01, vv, wr[0]);
        pk_fma_vs(o23, vv, wr[1]);
    }

    if (id < n) {
        float r = 1.f / (1.f + expf(-o01.x));
        float g = 1.f / (1.f + expf(-o01.y));
        float b = 1.f / (1.f + expf(-o23.x));
        float d = expf(o23.y - 1.f) * (sel ? 1.f : 0.f);
        out[3 * (size_t)i + 0] = r;
        out[3 * (size_t)i + 1] = g;
        out[3 * (size_t)i + 2] = b;
        out[3 * (size_t)n + i] = d;
    }
}

// ---------------- Fallback: fused kernel (if ws too small) -----------------
__global__ __launch_bounds__(256) void hashgrid_fused_kernel(
    const float* __restrict__ pos, const float* __restrict__ table,
    const float* __restrict__ W0, const float* __restrict__ W1,
    const float* __restrict__ W2, const float* __restrict__ W3,
    float* __restrict__ out, int n)
{
    int id = blockIdx.x * 256 + threadIdx.x;
    int i = id < n ? id : n - 1;

    float x = (pos[3 * i + 0] + 1.f) * 0.5f;
    float y = (pos[3 * i + 1] + 1.f) * 0.5f;
    float z = (pos[3 * i + 2] + 1.f) * 0.5f;
    bool sel = (x > 0.f) && (x < 1.f) && (y > 0.f) && (y < 1.f) &&
               (z > 0.f) && (z < 1.f);

    float h0[64];
#pragma unroll
    for (int j = 0; j < 64; ++j) h0[j] = 0.f;

    const float2* tb = (const float2*)table;
#pragma unroll
    for (int l = 0; l < NLEV; ++l) {
        float r = c_res[l];
        float sx = x * r, sy = y * r, sz = z * r;
        float fx = floorf(sx), fy = floorf(sy), fz = floorf(sz);
        float wx = sx - fx, wy = sy - fy, wz = sz - fz;
        unsigned ix = (unsigned)fx, iy = (unsigned)fy, iz = (unsigned)fz;
        unsigned hy0 = iy * P1, hy1 = hy0 + P1;
        unsigned hz0 = iz * P2, hz1 = hz0 + P2;
        unsigned a00 = hy0 ^ hz0, a10 = hy1 ^ hz0;
        unsigned a01 = hy0 ^ hz1, a11 = hy1 ^ hz1;
        unsigned ix1 = ix + 1u;
        const float2* tl = tb + (size_t)l * TSIZE;
        float2 e000 = tl[(ix  ^ a00) & TMASK];
        float2 e100 = tl[(ix1 ^ a00) & TMASK];
        float2 e010 = tl[(ix  ^ a10) & TMASK];
        float2 e110 = tl[(ix1 ^ a10) & TMASK];
        float2 e001 = tl[(ix  ^ a01) & TMASK];
        float2 e101 = tl[(ix1 ^ a01) & TMASK];
        float2 e011 = tl[(ix  ^ a11) & TMASK];
        float2 e111 = tl[(ix1 ^ a11) & TMASK];

        float ux = 1.f - wx, uy = 1.f - wy, uz = 1.f - wz;
        float w000 = ux * uy * uz, w100 = wx * uy * uz;
        float w010 = ux * wy * uz, w110 = wx * wy * uz;
        float w001 = ux * uy * wz, w101 = wx * uy * wz;
        float w011 = ux * wy * wz, w111 = wx * wy * wz;

        float f0 = e000.x * w000 + e100.x * w100 + e010.x * w010 + e110.x * w110 +
                   e001.x * w001 + e101.x * w101 + e011.x * w011 + e111.x * w111;
        float f1 = e000.y * w000 + e100.y * w100 + e010.y * w010 + e110.y * w110 +
                   e001.y * w001 + e101.y * w101 + e011.y * w011 + e111.y * w111;

        const float* w0a = W0 + (2 * l) * 64;
        const float* w0b = W0 + (2 * l + 1) * 64;
#pragma unroll
        for (int j = 0; j < 64; ++j)
            h0[j] = fmaf(f0, w0a[j], fmaf(f1, w0b[j], h0[j]));
    }
#pragma unroll
    for (int j = 0; j < 64; ++j) h0[j] = fmaxf(h0[j], 0.f);

    float h1[64];
#pragma unroll
    for (int j = 0; j < 64; ++j) h1[j] = 0.f;
#pragma unroll
    for (int k = 0; k < 64; ++k) {
        float v = h0[k];
        const float* wr = W1 + k * 64;
#pragma unroll
        for (int j = 0; j < 64; ++j) h1[j] = fmaf(v, wr[j], h1[j]);
    }
#pragma unroll
    for (int j = 0; j < 64; ++j) h1[j] = fmaxf(h1[j], 0.f);

#pragma unroll
    for (int j = 0; j < 64; ++j) h0[j] = 0.f;
#pragma unroll
    for (int k = 0; k < 64; ++k) {
        float v = h1[k];
        const float* wr = W2 + k * 64;
#pragma unroll
        for (int j = 0; j < 64; ++j) h0[j] = fmaf(v, wr[j], h0[j]);
    }
#pragma unroll
    for (int j = 0; j < 64; ++j) h0[j] = fmaxf(h0[j], 0.f);

    float o0 = 0.f, o1 = 0.f, o2 = 0.f, o3 = 0.f;
#pragma unroll
    for (int k = 0; k < 64; ++k) {
        float v = h0[k];
        const float* wr = W3 + k * 4;
        o0 = fmaf(v, wr[0], o0);
        o1 = fmaf(v, wr[1], o1);
        o2 = fmaf(v, wr[2], o2);
        o3 = fmaf(v, wr[3], o3);
    }

    if (id < n) {
        float r = 1.f / (1.f + expf(-o0));
        float g = 1.f / (1.f + expf(-o1));
        float b = 1.f / (1.f + expf(-o2));
        float d = expf(o3 - 1.f) * (sel ? 1.f : 0.f);
        out[3 * (size_t)i + 0] = r;
        out[3 * (size_t)i + 1] = g;
        out[3 * (size_t)i + 2] = b;
        out[3 * (size_t)n + i] = d;
    }
}

extern "C" void kernel_launch(void* const* d_in, const int* in_sizes, int n_in,
                              void* d_out, int out_size, void* d_ws, size_t ws_size,
                              hipStream_t stream) {
    const float* pos   = (const float*)d_in[0];
    const float* table = (const float*)d_in[1];
    const float* W0    = (const float*)d_in[2];
    const float* W1    = (const float*)d_in[3];
    const float* W2    = (const float*)d_in[4];
    const float* W3    = (const float*)d_in[5];
    float* out = (float*)d_out;
    int n = in_sizes[0] / 3;
    unsigned bpl = (unsigned)((n + 255) / 256);

    size_t feat_bytes = (size_t)NLEV * n * sizeof(__hip_bfloat162);
    if (ws_size >= feat_bytes) {
        __hip_bfloat162* feat = (__hip_bfloat162*)d_ws;
        hipLaunchKernelGGL(hash_encode_kernel, dim3(16 * bpl), dim3(256), 0, stream,
                           pos, table, feat, n, bpl);
        hipLaunchKernelGGL(mlp_kernel, dim3(bpl), dim3(256), 0, stream,
                           pos, feat, W0, W1, W2, W3, out, n);
    } else {
        hipLaunchKernelGGL(hashgrid_fused_kernel, dim3(bpl), dim3(256), 0, stream,
                           pos, table, W0, W1, W2, W3, out, n);
    }
}

// Round 4
// 252.241 us; speedup vs baseline: 2.0930x; 2.0930x over previous
//
#include <hip/hip_runtime.h>
#include <hip/hip_bf16.h>

#define NLEV 16
#define TSIZE (1u << 19)
#define TMASK ((1u << 19) - 1u)
#define P1 2654435761u
#define P2 805459861u

typedef __attribute__((ext_vector_type(8))) short short8;
typedef __attribute__((ext_vector_type(4))) float f32x4;

// floor(16 * b^l), b = 256^(1/15) — matches numpy float64 computation.
__device__ __constant__ float c_res[NLEV] = {
    16.f, 23.f, 33.f, 48.f, 70.f, 101.f, 147.f, 212.f,
    307.f, 445.f, 645.f, 933.f, 1351.f, 1955.f, 2830.f, 4096.f};

__device__ __forceinline__ short bf16_bits(float v) {
    __hip_bfloat16 h = __float2bfloat16(v);
    unsigned short us;
    __builtin_memcpy(&us, &h, 2);
    return (short)us;
}

__device__ __forceinline__ unsigned pack2_bf16(float lo, float hi) {
    unsigned a = (unsigned short)bf16_bits(lo);
    unsigned b = (unsigned short)bf16_bits(hi);
    return a | (b << 16);
}

// ---------------- Phase 1: hash encode, thread per (point, level) ----------
// XCD-pinned levels (kept from round 3: 214 -> ~167 us).
__global__ __launch_bounds__(256) void hash_encode_kernel(
    const float* __restrict__ pos,      // [N,3]
    const float* __restrict__ table,    // [16, 2^19, 2]
    __hip_bfloat162* __restrict__ feat, // [16][N] level-major
    int n, unsigned bpl)                // bpl = blocks per level
{
    unsigned b = blockIdx.x;
    unsigned slot = b & 7u;
    unsigned jj = b >> 3u;
    unsigned l = slot + 8u * (jj / bpl);
    unsigned pblk = jj % bpl;
    int i = (int)(pblk * 256u + threadIdx.x);
    if (i >= n) return;

    float x = (pos[3 * i + 0] + 1.f) * 0.5f;
    float y = (pos[3 * i + 1] + 1.f) * 0.5f;
    float z = (pos[3 * i + 2] + 1.f) * 0.5f;

    float r = c_res[l];
    float sx = x * r, sy = y * r, sz = z * r;
    float fx = floorf(sx), fy = floorf(sy), fz = floorf(sz);
    float wx = sx - fx, wy = sy - fy, wz = sz - fz;
    unsigned ix = (unsigned)fx, iy = (unsigned)fy, iz = (unsigned)fz;
    unsigned hy0 = iy * P1, hy1 = hy0 + P1;
    unsigned hz0 = iz * P2, hz1 = hz0 + P2;
    unsigned a00 = hy0 ^ hz0, a10 = hy1 ^ hz0;
    unsigned a01 = hy0 ^ hz1, a11 = hy1 ^ hz1;
    unsigned ix1 = ix + 1u;

    const float2* tl = (const float2*)table + (size_t)l * TSIZE;
    float2 e000 = tl[(ix  ^ a00) & TMASK];
    float2 e100 = tl[(ix1 ^ a00) & TMASK];
    float2 e010 = tl[(ix  ^ a10) & TMASK];
    float2 e110 = tl[(ix1 ^ a10) & TMASK];
    float2 e001 = tl[(ix  ^ a01) & TMASK];
    float2 e101 = tl[(ix1 ^ a01) & TMASK];
    float2 e011 = tl[(ix  ^ a11) & TMASK];
    float2 e111 = tl[(ix1 ^ a11) & TMASK];

    float ux = 1.f - wx, uy = 1.f - wy, uz = 1.f - wz;
    float w000 = ux * uy * uz, w100 = wx * uy * uz;
    float w010 = ux * wy * uz, w110 = wx * wy * uz;
    float w001 = ux * uy * wz, w101 = wx * uy * wz;
    float w011 = ux * wy * wz, w111 = wx * wy * wz;

    float f0 = e000.x * w000 + e100.x * w100 + e010.x * w010 + e110.x * w110 +
               e001.x * w001 + e101.x * w101 + e011.x * w011 + e111.x * w111;
    float f1 = e000.y * w000 + e100.y * w100 + e010.y * w010 + e110.y * w110 +
               e001.y * w001 + e101.y * w101 + e011.y * w011 + e111.y * w111;

    __hip_bfloat162 v;
    v.x = __float2bfloat16(f0);
    v.y = __float2bfloat16(f1);
    feat[(size_t)l * n + i] = v;
}

// ---------------- Phase 2: bf16 MFMA MLP -----------------------------------
// Computes H^T = W^T * X^T per 16-point tile with mfma_f32_16x16x32_bf16.
// Weights hoisted as A-frags (A[i][k]: i = lane&15 = out-neuron, k = 8*(lane>>4)+jj).
// Activations live in a per-wave 16x128B LDS buffer; XOR-block swizzle keeps
// ds_write_b64 / ds_read_b128 bank-uniform. A/B use the SAME k-slot mapping,
// so any k-permutation uncertainty cancels; C/D mapping is HW-verified (m89).

__device__ __forceinline__ void store_H(char* hrow, int g, int swz, f32x4* acc) {
#pragma unroll
    for (int mt = 0; mt < 4; ++mt) {
        float v0 = fmaxf(acc[mt][0], 0.f), v1 = fmaxf(acc[mt][1], 0.f);
        float v2 = fmaxf(acc[mt][2], 0.f), v3 = fmaxf(acc[mt][3], 0.f);
        unsigned lo = pack2_bf16(v0, v1);
        unsigned hi = pack2_bf16(v2, v3);
        int blk = (2 * mt + (g >> 1)) ^ swz;
        *(uint2*)(hrow + blk * 16 + (g & 1) * 8) = make_uint2(lo, hi);
    }
}

__global__ __launch_bounds__(256) void mlp_mfma_kernel(
    const float* __restrict__ pos,
    const unsigned* __restrict__ feat,  // [16][n] u32 = bf16x2
    const float* __restrict__ W0,       // [32,64]
    const float* __restrict__ W1,       // [64,64]
    const float* __restrict__ W2,       // [64,64]
    const float* __restrict__ W3,       // [64,4]
    float* __restrict__ out, int n, int nchunks)
{
    __shared__ char hlds[4 * 16 * 128];
    const int tid  = threadIdx.x;
    const int w    = tid >> 6;
    const int lane = tid & 63;
    const int g    = lane >> 4;
    const int p    = lane & 15;
    char* hrow = hlds + w * (16 * 128) + p * 128;
    const int swz = p & 7;

    // ---- hoist weight fragments (bf16) ----
    short8 a0[4], a1[4][2], a2[4][2], a3[2];
#pragma unroll
    for (int mt = 0; mt < 4; ++mt)
#pragma unroll
        for (int jj = 0; jj < 8; ++jj)
            a0[mt][jj] = bf16_bits(W0[(8 * g + jj) * 64 + 16 * mt + p]);
#pragma unroll
    for (int mt = 0; mt < 4; ++mt)
#pragma unroll
        for (int kt = 0; kt < 2; ++kt)
#pragma unroll
            for (int jj = 0; jj < 8; ++jj) {
                a1[mt][kt][jj] = bf16_bits(W1[(32 * kt + 8 * g + jj) * 64 + 16 * mt + p]);
                a2[mt][kt][jj] = bf16_bits(W2[(32 * kt + 8 * g + jj) * 64 + 16 * mt + p]);
            }
#pragma unroll
    for (int kt = 0; kt < 2; ++kt)
#pragma unroll
        for (int jj = 0; jj < 8; ++jj)
            a3[kt][jj] = (p < 4) ? bf16_bits(W3[(32 * kt + 8 * g + jj) * 4 + p]) : (short)0;

    const f32x4 zf = {0.f, 0.f, 0.f, 0.f};

    for (int c = blockIdx.x; c < nchunks; c += gridDim.x) {
        const int base = c * 256 + w * 64;
        for (int t = 0; t < 4; ++t) {
            const int ptg = base + t * 16 + p;
            const int ptc = ptg < n ? ptg : n - 1;

            // layer-0 B-frag: 4 coalesced dwords from the level planes
            union { unsigned u[4]; short8 s; } bu;
#pragma unroll
            for (int m = 0; m < 4; ++m)
                bu.u[m] = feat[(size_t)(4 * g + m) * (size_t)n + ptc];

            f32x4 acc[4];
#pragma unroll
            for (int mt = 0; mt < 4; ++mt)
                acc[mt] = __builtin_amdgcn_mfma_f32_16x16x32_bf16(a0[mt], bu.s, zf, 0, 0, 0);

            store_H(hrow, g, swz, acc);
            short8 b0 = *(const short8*)(hrow + ((g ^ swz) << 4));
            short8 b1 = *(const short8*)(hrow + (((4 + g) ^ swz) << 4));

#pragma unroll
            for (int mt = 0; mt < 4; ++mt) {
                acc[mt] = __builtin_amdgcn_mfma_f32_16x16x32_bf16(a1[mt][0], b0, zf, 0, 0, 0);
                acc[mt] = __builtin_amdgcn_mfma_f32_16x16x32_bf16(a1[mt][1], b1, acc[mt], 0, 0, 0);
            }

            store_H(hrow, g, swz, acc);
            b0 = *(const short8*)(hrow + ((g ^ swz) << 4));
            b1 = *(const short8*)(hrow + (((4 + g) ^ swz) << 4));

#pragma unroll
            for (int mt = 0; mt < 4; ++mt) {
                acc[mt] = __builtin_amdgcn_mfma_f32_16x16x32_bf16(a2[mt][0], b0, zf, 0, 0, 0);
                acc[mt] = __builtin_amdgcn_mfma_f32_16x16x32_bf16(a2[mt][1], b1, acc[mt], 0, 0, 0);
            }

            store_H(hrow, g, swz, acc);
            b0 = *(const short8*)(hrow + ((g ^ swz) << 4));
            b1 = *(const short8*)(hrow + (((4 + g) ^ swz) << 4));

            f32x4 o = __builtin_amdgcn_mfma_f32_16x16x32_bf16(a3[0], b0, zf, 0, 0, 0);
            o = __builtin_amdgcn_mfma_f32_16x16x32_bf16(a3[1], b1, o, 0, 0, 0);

            if (g == 0 && ptg < n) {
                float px = pos[3 * ptg + 0];
                float py = pos[3 * ptg + 1];
                float pz = pos[3 * ptg + 2];
                float xx = (px + 1.f) * 0.5f;
                float yy = (py + 1.f) * 0.5f;
                float zz = (pz + 1.f) * 0.5f;
                bool sel = (xx > 0.f) && (xx < 1.f) && (yy > 0.f) && (yy < 1.f) &&
                           (zz > 0.f) && (zz < 1.f);
                out[3 * (size_t)ptg + 0] = 1.f / (1.f + expf(-o[0]));
                out[3 * (size_t)ptg + 1] = 1.f / (1.f + expf(-o[1]));
                out[3 * (size_t)ptg + 2] = 1.f / (1.f + expf(-o[2]));
                out[3 * (size_t)n + ptg] = expf(o[3] - 1.f) * (sel ? 1.f : 0.f);
            }
        }
    }
}

// ---------------- Fallback: fused scalar kernel (if ws too small) ----------
__global__ __launch_bounds__(256) void hashgrid_fused_kernel(
    const float* __restrict__ pos, const float* __restrict__ table,
    const float* __restrict__ W0, const float* __restrict__ W1,
    const float* __restrict__ W2, const float* __restrict__ W3,
    float* __restrict__ out, int n)
{
    int id = blockIdx.x * 256 + threadIdx.x;
    int i = id < n ? id : n - 1;

    float x = (pos[3 * i + 0] + 1.f) * 0.5f;
    float y = (pos[3 * i + 1] + 1.f) * 0.5f;
    float z = (pos[3 * i + 2] + 1.f) * 0.5f;
    bool sel = (x > 0.f) && (x < 1.f) && (y > 0.f) && (y < 1.f) &&
               (z > 0.f) && (z < 1.f);

    float h0[64];
#pragma unroll
    for (int j = 0; j < 64; ++j) h0[j] = 0.f;

    const float2* tb = (const float2*)table;
#pragma unroll
    for (int l = 0; l < NLEV; ++l) {
        float r = c_res[l];
        float sx = x * r, sy = y * r, sz = z * r;
        float fx = floorf(sx), fy = floorf(sy), fz = floorf(sz);
        float wx = sx - fx, wy = sy - fy, wz = sz - fz;
        unsigned ix = (unsigned)fx, iy = (unsigned)fy, iz = (unsigned)fz;
        unsigned hy0 = iy * P1, hy1 = hy0 + P1;
        unsigned hz0 = iz * P2, hz1 = hz0 + P2;
        unsigned a00 = hy0 ^ hz0, a10 = hy1 ^ hz0;
        unsigned a01 = hy0 ^ hz1, a11 = hy1 ^ hz1;
        unsigned ix1 = ix + 1u;
        const float2* tl = tb + (size_t)l * TSIZE;
        float2 e000 = tl[(ix  ^ a00) & TMASK];
        float2 e100 = tl[(ix1 ^ a00) & TMASK];
        float2 e010 = tl[(ix  ^ a10) & TMASK];
        float2 e110 = tl[(ix1 ^ a10) & TMASK];
        float2 e001 = tl[(ix  ^ a01) & TMASK];
        float2 e101 = tl[(ix1 ^ a01) & TMASK];
        float2 e011 = tl[(ix  ^ a11) & TMASK];
        float2 e111 = tl[(ix1 ^ a11) & TMASK];

        float ux = 1.f - wx, uy = 1.f - wy, uz = 1.f - wz;
        float w000 = ux * uy * uz, w100 = wx * uy * uz;
        float w010 = ux * wy * uz, w110 = wx * wy * uz;
        float w001 = ux * uy * wz, w101 = wx * uy * wz;
        float w011 = ux * wy * wz, w111 = wx * wy * wz;

        float f0 = e000.x * w000 + e100.x * w100 + e010.x * w010 + e110.x * w110 +
                   e001.x * w001 + e101.x * w101 + e011.x * w011 + e111.x * w111;
        float f1 = e000.y * w000 + e100.y * w100 + e010.y * w010 + e110.y * w110 +
                   e001.y * w001 + e101.y * w101 + e011.y * w011 + e111.y * w111;

        const float* w0a = W0 + (2 * l) * 64;
        const float* w0b = W0 + (2 * l + 1) * 64;
#pragma unroll
        for (int j = 0; j < 64; ++j)
            h0[j] = fmaf(f0, w0a[j], fmaf(f1, w0b[j], h0[j]));
    }
#pragma unroll
    for (int j = 0; j < 64; ++j) h0[j] = fmaxf(h0[j], 0.f);

    float h1[64];
#pragma unroll
    for (int j = 0; j < 64; ++j) h1[j] = 0.f;
#pragma unroll
    for (int k = 0; k < 64; ++k) {
        float v = h0[k];
        const float* wr = W1 + k * 64;
#pragma unroll
        for (int j = 0; j < 64; ++j) h1[j] = fmaf(v, wr[j], h1[j]);
    }
#pragma unroll
    for (int j = 0; j < 64; ++j) h1[j] = fmaxf(h1[j], 0.f);

#pragma unroll
    for (int j = 0; j < 64; ++j) h0[j] = 0.f;
#pragma unroll
    for (int k = 0; k < 64; ++k) {
        float v = h1[k];
        const float* wr = W2 + k * 64;
#pragma unroll
        for (int j = 0; j < 64; ++j) h0[j] = fmaf(v, wr[j], h0[j]);
    }
#pragma unroll
    for (int j = 0; j < 64; ++j) h0[j] = fmaxf(h0[j], 0.f);

    float o0 = 0.f, o1 = 0.f, o2 = 0.f, o3 = 0.f;
#pragma unroll
    for (int k = 0; k < 64; ++k) {
        float v = h0[k];
        const float* wr = W3 + k * 4;
        o0 = fmaf(v, wr[0], o0);
        o1 = fmaf(v, wr[1], o1);
        o2 = fmaf(v, wr[2], o2);
        o3 = fmaf(v, wr[3], o3);
    }

    if (id < n) {
        float r = 1.f / (1.f + expf(-o0));
        float g = 1.f / (1.f + expf(-o1));
        float b = 1.f / (1.f + expf(-o2));
        float d = expf(o3 - 1.f) * (sel ? 1.f : 0.f);
        out[3 * (size_t)i + 0] = r;
        out[3 * (size_t)i + 1] = g;
        out[3 * (size_t)i + 2] = b;
        out[3 * (size_t)n + i] = d;
    }
}

extern "C" void kernel_launch(void* const* d_in, const int* in_sizes, int n_in,
                              void* d_out, int out_size, void* d_ws, size_t ws_size,
                              hipStream_t stream) {
    const float* pos   = (const float*)d_in[0];
    const float* table = (const float*)d_in[1];
    const float* W0    = (const float*)d_in[2];
    const float* W1    = (const float*)d_in[3];
    const float* W2    = (const float*)d_in[4];
    const float* W3    = (const float*)d_in[5];
    float* out = (float*)d_out;
    int n = in_sizes[0] / 3;
    unsigned bpl = (unsigned)((n + 255) / 256);
    int nchunks = (n + 255) / 256;

    size_t feat_bytes = (size_t)NLEV * n * sizeof(__hip_bfloat162);
    if (ws_size >= feat_bytes) {
        __hip_bfloat162* feat = (__hip_bfloat162*)d_ws;
        hipLaunchKernelGGL(hash_encode_kernel, dim3(16 * bpl), dim3(256), 0, stream,
                           pos, table, feat, n, bpl);
        int mblocks = nchunks < 512 ? nchunks : 512;
        hipLaunchKernelGGL(mlp_mfma_kernel, dim3(mblocks), dim3(256), 0, stream,
                           pos, (const unsigned*)feat, W0, W1, W2, W3, out, n, nchunks);
    } else {
        hipLaunchKernelGGL(hashgrid_fused_kernel, dim3(bpl), dim3(256), 0, stream,
                           pos, table, W0, W1, W2, W3, out, n);
    }
}

// Round 5
// 218.051 us; speedup vs baseline: 2.4212x; 1.1568x over previous
//
#include <hip/hip_runtime.h>
#include <hip/hip_bf16.h>

#define NLEV 16
#define TSIZE (1u << 19)
#define TMASK ((1u << 19) - 1u)
#define P1 2654435761u
#define P2 805459861u

typedef __attribute__((ext_vector_type(8))) short short8;
typedef __attribute__((ext_vector_type(4))) float f32x4;

// floor(16 * b^l), b = 256^(1/15) — matches numpy float64 computation.
__device__ __constant__ float c_res[NLEV] = {
    16.f, 23.f, 33.f, 48.f, 70.f, 101.f, 147.f, 212.f,
    307.f, 445.f, 645.f, 933.f, 1351.f, 1955.f, 2830.f, 4096.f};

__device__ __forceinline__ short bf16_bits(float v) {
    __hip_bfloat16 h = __float2bfloat16(v);
    unsigned short us;
    __builtin_memcpy(&us, &h, 2);
    return (short)us;
}

__device__ __forceinline__ unsigned pack2_bf16(float lo, float hi) {
    unsigned a = (unsigned short)bf16_bits(lo);
    unsigned b = (unsigned short)bf16_bits(hi);
    return a | (b << 16);
}

__device__ __forceinline__ float bf_lo(unsigned u) {
    unsigned v = u << 16;
    float f;
    __builtin_memcpy(&f, &v, 4);
    return f;
}
__device__ __forceinline__ float bf_hi(unsigned u) {
    unsigned v = u & 0xffff0000u;
    float f;
    __builtin_memcpy(&f, &v, 4);
    return f;
}

// ---------------- Phase 0: build pair-duplicated bf16 table ----------------
// pair[l][j] = (bf16x2(entry[l][j]), bf16x2(entry[l][j^1]))  -> 8 B per slot.
// One coalesced 8B load + shfl_xor(1) + 8B store per thread.
__global__ __launch_bounds__(256) void convert_table_kernel(
    const float2* __restrict__ table, uint2* __restrict__ pair, int total)
{
    for (int i = blockIdx.x * 256 + threadIdx.x; i < total; i += gridDim.x * 256) {
        float2 e = table[i];
        unsigned a = pack2_bf16(e.x, e.y);
        unsigned b = __shfl_xor(a, 1);   // lane i^1 holds entry i^1
        pair[i] = make_uint2(a, b);
    }
}

// ---------------- Phase 1: hash encode, 4 paired gathers per level ---------
// XCD-pinned levels: block b -> slot b%8; levels {slot, slot+8} sequential.
__global__ __launch_bounds__(256) void hash_encode_pair_kernel(
    const float* __restrict__ pos,      // [N,3]
    const uint2* __restrict__ pair,     // [16][2^19] pair-duplicated bf16
    __hip_bfloat162* __restrict__ feat, // [16][N] level-major
    int n, unsigned bpl)
{
    unsigned b = blockIdx.x;
    unsigned slot = b & 7u;
    unsigned jj = b >> 3u;
    unsigned l = slot + 8u * (jj / bpl);
    unsigned pblk = jj % bpl;
    int i = (int)(pblk * 256u + threadIdx.x);
    if (i >= n) return;

    float x = (pos[3 * i + 0] + 1.f) * 0.5f;
    float y = (pos[3 * i + 1] + 1.f) * 0.5f;
    float z = (pos[3 * i + 2] + 1.f) * 0.5f;

    float r = c_res[l];
    float sx = x * r, sy = y * r, sz = z * r;
    float fx = floorf(sx), fy = floorf(sy), fz = floorf(sz);
    float wx = sx - fx, wy = sy - fy, wz = sz - fz;
    unsigned ix = (unsigned)fx, iy = (unsigned)fy, iz = (unsigned)fz;
    unsigned hy0 = iy * P1, hy1 = hy0 + P1;
    unsigned hz0 = iz * P2, hz1 = hz0 + P2;
    unsigned a00 = hy0 ^ hz0, a10 = hy1 ^ hz0;
    unsigned a01 = hy0 ^ hz1, a11 = hy1 ^ hz1;

    unsigned sel = ix & 1u;              // parity of low x corner
    unsigned jx = ix + sel;              // even-partner index covering both corners

    const uint2* tl = pair + (size_t)l * TSIZE;
    uint2 g00 = tl[(jx ^ a00) & TMASK];
    uint2 g10 = tl[(jx ^ a10) & TMASK];
    uint2 g01 = tl[(jx ^ a01) & TMASK];
    uint2 g11 = tl[(jx ^ a11) & TMASK];

    // order within pair: .x = entry[j] (x-index jx), .y = entry[j^1] (x-index jx^1)
    // low x corner (ix):   sel ? g.y : g.x ;  high (ix+1): sel ? g.x : g.y
    unsigned e0_00 = sel ? g00.y : g00.x, e1_00 = sel ? g00.x : g00.y;
    unsigned e0_10 = sel ? g10.y : g10.x, e1_10 = sel ? g10.x : g10.y;
    unsigned e0_01 = sel ? g01.y : g01.x, e1_01 = sel ? g01.x : g01.y;
    unsigned e0_11 = sel ? g11.y : g11.x, e1_11 = sel ? g11.x : g11.y;

    float ux = 1.f - wx, uy = 1.f - wy, uz = 1.f - wz;
    float w000 = ux * uy * uz, w100 = wx * uy * uz;
    float w010 = ux * wy * uz, w110 = wx * wy * uz;
    float w001 = ux * uy * wz, w101 = wx * uy * wz;
    float w011 = ux * wy * wz, w111 = wx * wy * wz;

    float f0 = bf_lo(e0_00) * w000 + bf_lo(e1_00) * w100 +
               bf_lo(e0_10) * w010 + bf_lo(e1_10) * w110 +
               bf_lo(e0_01) * w001 + bf_lo(e1_01) * w101 +
               bf_lo(e0_11) * w011 + bf_lo(e1_11) * w111;
    float f1 = bf_hi(e0_00) * w000 + bf_hi(e1_00) * w100 +
               bf_hi(e0_10) * w010 + bf_hi(e1_10) * w110 +
               bf_hi(e0_01) * w001 + bf_hi(e1_01) * w101 +
               bf_hi(e0_11) * w011 + bf_hi(e1_11) * w111;

    __hip_bfloat162 v;
    v.x = __float2bfloat16(f0);
    v.y = __float2bfloat16(f1);
    feat[(size_t)l * n + i] = v;
}

// ---------------- Phase 1 fallback (round-4): fp32 table, 8 gathers --------
__global__ __launch_bounds__(256) void hash_encode_kernel(
    const float* __restrict__ pos,
    const float* __restrict__ table,
    __hip_bfloat162* __restrict__ feat,
    int n, unsigned bpl)
{
    unsigned b = blockIdx.x;
    unsigned slot = b & 7u;
    unsigned jj = b >> 3u;
    unsigned l = slot + 8u * (jj / bpl);
    unsigned pblk = jj % bpl;
    int i = (int)(pblk * 256u + threadIdx.x);
    if (i >= n) return;

    float x = (pos[3 * i + 0] + 1.f) * 0.5f;
    float y = (pos[3 * i + 1] + 1.f) * 0.5f;
    float z = (pos[3 * i + 2] + 1.f) * 0.5f;

    float r = c_res[l];
    float sx = x * r, sy = y * r, sz = z * r;
    float fx = floorf(sx), fy = floorf(sy), fz = floorf(sz);
    float wx = sx - fx, wy = sy - fy, wz = sz - fz;
    unsigned ix = (unsigned)fx, iy = (unsigned)fy, iz = (unsigned)fz;
    unsigned hy0 = iy * P1, hy1 = hy0 + P1;
    unsigned hz0 = iz * P2, hz1 = hz0 + P2;
    unsigned a00 = hy0 ^ hz0, a10 = hy1 ^ hz0;
    unsigned a01 = hy0 ^ hz1, a11 = hy1 ^ hz1;
    unsigned ix1 = ix + 1u;

    const float2* tl = (const float2*)table + (size_t)l * TSIZE;
    float2 e000 = tl[(ix  ^ a00) & TMASK];
    float2 e100 = tl[(ix1 ^ a00) & TMASK];
    float2 e010 = tl[(ix  ^ a10) & TMASK];
    float2 e110 = tl[(ix1 ^ a10) & TMASK];
    float2 e001 = tl[(ix  ^ a01) & TMASK];
    float2 e101 = tl[(ix1 ^ a01) & TMASK];
    float2 e011 = tl[(ix  ^ a11) & TMASK];
    float2 e111 = tl[(ix1 ^ a11) & TMASK];

    float ux = 1.f - wx, uy = 1.f - wy, uz = 1.f - wz;
    float w000 = ux * uy * uz, w100 = wx * uy * uz;
    float w010 = ux * wy * uz, w110 = wx * wy * uz;
    float w001 = ux * uy * wz, w101 = wx * uy * wz;
    float w011 = ux * wy * wz, w111 = wx * wy * wz;

    float f0 = e000.x * w000 + e100.x * w100 + e010.x * w010 + e110.x * w110 +
               e001.x * w001 + e101.x * w101 + e011.x * w011 + e111.x * w111;
    float f1 = e000.y * w000 + e100.y * w100 + e010.y * w010 + e110.y * w110 +
               e001.y * w001 + e101.y * w101 + e011.y * w011 + e111.y * w111;

    __hip_bfloat162 v;
    v.x = __float2bfloat16(f0);
    v.y = __float2bfloat16(f1);
    feat[(size_t)l * n + i] = v;
}

// ---------------- Phase 2: bf16 MFMA MLP (unchanged from round 4) ----------
__device__ __forceinline__ void store_H(char* hrow, int g, int swz, f32x4* acc) {
#pragma unroll
    for (int mt = 0; mt < 4; ++mt) {
        float v0 = fmaxf(acc[mt][0], 0.f), v1 = fmaxf(acc[mt][1], 0.f);
        float v2 = fmaxf(acc[mt][2], 0.f), v3 = fmaxf(acc[mt][3], 0.f);
        unsigned lo = pack2_bf16(v0, v1);
        unsigned hi = pack2_bf16(v2, v3);
        int blk = (2 * mt + (g >> 1)) ^ swz;
        *(uint2*)(hrow + blk * 16 + (g & 1) * 8) = make_uint2(lo, hi);
    }
}

__global__ __launch_bounds__(256) void mlp_mfma_kernel(
    const float* __restrict__ pos,
    const unsigned* __restrict__ feat,  // [16][n] u32 = bf16x2
    const float* __restrict__ W0,
    const float* __restrict__ W1,
    const float* __restrict__ W2,
    const float* __restrict__ W3,
    float* __restrict__ out, int n, int nchunks)
{
    __shared__ char hlds[4 * 16 * 128];
    const int tid  = threadIdx.x;
    const int w    = tid >> 6;
    const int lane = tid & 63;
    const int g    = lane >> 4;
    const int p    = lane & 15;
    char* hrow = hlds + w * (16 * 128) + p * 128;
    const int swz = p & 7;

    short8 a0[4], a1[4][2], a2[4][2], a3[2];
#pragma unroll
    for (int mt = 0; mt < 4; ++mt)
#pragma unroll
        for (int jj = 0; jj < 8; ++jj)
            a0[mt][jj] = bf16_bits(W0[(8 * g + jj) * 64 + 16 * mt + p]);
#pragma unroll
    for (int mt = 0; mt < 4; ++mt)
#pragma unroll
        for (int kt = 0; kt < 2; ++kt)
#pragma unroll
            for (int jj = 0; jj < 8; ++jj) {
                a1[mt][kt][jj] = bf16_bits(W1[(32 * kt + 8 * g + jj) * 64 + 16 * mt + p]);
                a2[mt][kt][jj] = bf16_bits(W2[(32 * kt + 8 * g + jj) * 64 + 16 * mt + p]);
            }
#pragma unroll
    for (int kt = 0; kt < 2; ++kt)
#pragma unroll
        for (int jj = 0; jj < 8; ++jj)
            a3[kt][jj] = (p < 4) ? bf16_bits(W3[(32 * kt + 8 * g + jj) * 4 + p]) : (short)0;

    const f32x4 zf = {0.f, 0.f, 0.f, 0.f};

    for (int c = blockIdx.x; c < nchunks; c += gridDim.x) {
        const int base = c * 256 + w * 64;
        for (int t = 0; t < 4; ++t) {
            const int ptg = base + t * 16 + p;
            const int ptc = ptg < n ? ptg : n - 1;

            union { unsigned u[4]; short8 s; } bu;
#pragma unroll
            for (int m = 0; m < 4; ++m)
                bu.u[m] = feat[(size_t)(4 * g + m) * (size_t)n + ptc];

            f32x4 acc[4];
#pragma unroll
            for (int mt = 0; mt < 4; ++mt)
                acc[mt] = __builtin_amdgcn_mfma_f32_16x16x32_bf16(a0[mt], bu.s, zf, 0, 0, 0);

            store_H(hrow, g, swz, acc);
            short8 b0 = *(const short8*)(hrow + ((g ^ swz) << 4));
            short8 b1 = *(const short8*)(hrow + (((4 + g) ^ swz) << 4));

#pragma unroll
            for (int mt = 0; mt < 4; ++mt) {
                acc[mt] = __builtin_amdgcn_mfma_f32_16x16x32_bf16(a1[mt][0], b0, zf, 0, 0, 0);
                acc[mt] = __builtin_amdgcn_mfma_f32_16x16x32_bf16(a1[mt][1], b1, acc[mt], 0, 0, 0);
            }

            store_H(hrow, g, swz, acc);
            b0 = *(const short8*)(hrow + ((g ^ swz) << 4));
            b1 = *(const short8*)(hrow + (((4 + g) ^ swz) << 4));

#pragma unroll
            for (int mt = 0; mt < 4; ++mt) {
                acc[mt] = __builtin_amdgcn_mfma_f32_16x16x32_bf16(a2[mt][0], b0, zf, 0, 0, 0);
                acc[mt] = __builtin_amdgcn_mfma_f32_16x16x32_bf16(a2[mt][1], b1, acc[mt], 0, 0, 0);
            }

            store_H(hrow, g, swz, acc);
            b0 = *(const short8*)(hrow + ((g ^ swz) << 4));
            b1 = *(const short8*)(hrow + (((4 + g) ^ swz) << 4));

            f32x4 o = __builtin_amdgcn_mfma_f32_16x16x32_bf16(a3[0], b0, zf, 0, 0, 0);
            o = __builtin_amdgcn_mfma_f32_16x16x32_bf16(a3[1], b1, o, 0, 0, 0);

            if (g == 0 && ptg < n) {
                float px = pos[3 * ptg + 0];
                float py = pos[3 * ptg + 1];
                float pz = pos[3 * ptg + 2];
                float xx = (px + 1.f) * 0.5f;
                float yy = (py + 1.f) * 0.5f;
                float zz = (pz + 1.f) * 0.5f;
                bool sel = (xx > 0.f) && (xx < 1.f) && (yy > 0.f) && (yy < 1.f) &&
                           (zz > 0.f) && (zz < 1.f);
                out[3 * (size_t)ptg + 0] = 1.f / (1.f + expf(-o[0]));
                out[3 * (size_t)ptg + 1] = 1.f / (1.f + expf(-o[1]));
                out[3 * (size_t)ptg + 2] = 1.f / (1.f + expf(-o[2]));
                out[3 * (size_t)n + ptg] = expf(o[3] - 1.f) * (sel ? 1.f : 0.f);
            }
        }
    }
}

// ---------------- Fallback: fused scalar kernel (if ws too small) ----------
__global__ __launch_bounds__(256) void hashgrid_fused_kernel(
    const float* __restrict__ pos, const float* __restrict__ table,
    const float* __restrict__ W0, const float* __restrict__ W1,
    const float* __restrict__ W2, const float* __restrict__ W3,
    float* __restrict__ out, int n)
{
    int id = blockIdx.x * 256 + threadIdx.x;
    int i = id < n ? id : n - 1;

    float x = (pos[3 * i + 0] + 1.f) * 0.5f;
    float y = (pos[3 * i + 1] + 1.f) * 0.5f;
    float z = (pos[3 * i + 2] + 1.f) * 0.5f;
    bool sel = (x > 0.f) && (x < 1.f) && (y > 0.f) && (y < 1.f) &&
               (z > 0.f) && (z < 1.f);

    float h0[64];
#pragma unroll
    for (int j = 0; j < 64; ++j) h0[j] = 0.f;

    const float2* tb = (const float2*)table;
#pragma unroll
    for (int l = 0; l < NLEV; ++l) {
        float r = c_res[l];
        float sx = x * r, sy = y * r, sz = z * r;
        float fx = floorf(sx), fy = floorf(sy), fz = floorf(sz);
        float wx = sx - fx, wy = sy - fy, wz = sz - fz;
        unsigned ix = (unsigned)fx, iy = (unsigned)fy, iz = (unsigned)fz;
        unsigned hy0 = iy * P1, hy1 = hy0 + P1;
        unsigned hz0 = iz * P2, hz1 = hz0 + P2;
        unsigned a00 = hy0 ^ hz0, a10 = hy1 ^ hz0;
        unsigned a01 = hy0 ^ hz1, a11 = hy1 ^ hz1;
        unsigned ix1 = ix + 1u;
        const float2* tl = tb + (size_t)l * TSIZE;
        float2 e000 = tl[(ix  ^ a00) & TMASK];
        float2 e100 = tl[(ix1 ^ a00) & TMASK];
        float2 e010 = tl[(ix  ^ a10) & TMASK];
        float2 e110 = tl[(ix1 ^ a10) & TMASK];
        float2 e001 = tl[(ix  ^ a01) & TMASK];
        float2 e101 = tl[(ix1 ^ a01) & TMASK];
        float2 e011 = tl[(ix  ^ a11) & TMASK];
        float2 e111 = tl[(ix1 ^ a11) & TMASK];

        float ux = 1.f - wx, uy = 1.f - wy, uz = 1.f - wz;
        float w000 = ux * uy * uz, w100 = wx * uy * uz;
        float w010 = ux * wy * uz, w110 = wx * wy * uz;
        float w001 = ux * uy * wz, w101 = wx * uy * wz;
        float w011 = ux * wy * wz, w111 = wx * wy * wz;

        float f0 = e000.x * w000 + e100.x * w100 + e010.x * w010 + e110.x * w110 +
                   e001.x * w001 + e101.x * w101 + e011.x * w011 + e111.x * w111;
        float f1 = e000.y * w000 + e100.y * w100 + e010.y * w010 + e110.y * w110 +
                   e001.y * w001 + e101.y * w101 + e011.y * w011 + e111.y * w111;

        const float* w0a = W0 + (2 * l) * 64;
        const float* w0b = W0 + (2 * l + 1) * 64;
#pragma unroll
        for (int j = 0; j < 64; ++j)
            h0[j] = fmaf(f0, w0a[j], fmaf(f1, w0b[j], h0[j]));
    }
#pragma unroll
    for (int j = 0; j < 64; ++j) h0[j] = fmaxf(h0[j], 0.f);

    float h1[64];
#pragma unroll
    for (int j = 0; j < 64; ++j) h1[j] = 0.f;
#pragma unroll
    for (int k = 0; k < 64; ++k) {
        float v = h0[k];
        const float* wr = W1 + k * 64;
#pragma unroll
        for (int j = 0; j < 64; ++j) h1[j] = fmaf(v, wr[j], h1[j]);
    }
#pragma unroll
    for (int j = 0; j < 64; ++j) h1[j] = fmaxf(h1[j], 0.f);

#pragma unroll
    for (int j = 0; j < 64; ++j) h0[j] = 0.f;
#pragma unroll
    for (int k = 0; k < 64; ++k) {
        float v = h1[k];
        const float* wr = W2 + k * 64;
#pragma unroll
        for (int j = 0; j < 64; ++j) h0[j] = fmaf(v, wr[j], h0[j]);
    }
#pragma unroll
    for (int j = 0; j < 64; ++j) h0[j] = fmaxf(h0[j], 0.f);

    float o0 = 0.f, o1 = 0.f, o2 = 0.f, o3 = 0.f;
#pragma unroll
    for (int k = 0; k < 64; ++k) {
        float v = h0[k];
        const float* wr = W3 + k * 4;
        o0 = fmaf(v, wr[0], o0);
        o1 = fmaf(v, wr[1], o1);
        o2 = fmaf(v, wr[2], o2);
        o3 = fmaf(v, wr[3], o3);
    }

    if (id < n) {
        float r = 1.f / (1.f + expf(-o0));
        float g = 1.f / (1.f + expf(-o1));
        float b = 1.f / (1.f + expf(-o2));
        float d = expf(o3 - 1.f) * (sel ? 1.f : 0.f);
        out[3 * (size_t)i + 0] = r;
        out[3 * (size_t)i + 1] = g;
        out[3 * (size_t)i + 2] = b;
        out[3 * (size_t)n + i] = d;
    }
}

extern "C" void kernel_launch(void* const* d_in, const int* in_sizes, int n_in,
                              void* d_out, int out_size, void* d_ws, size_t ws_size,
                              hipStream_t stream) {
    const float* pos   = (const float*)d_in[0];
    const float* table = (const float*)d_in[1];
    const float* W0    = (const float*)d_in[2];
    const float* W1    = (const float*)d_in[3];
    const float* W2    = (const float*)d_in[4];
    const float* W3    = (const float*)d_in[5];
    float* out = (float*)d_out;
    int n = in_sizes[0] / 3;
    unsigned bpl = (unsigned)((n + 255) / 256);
    int nchunks = (n + 255) / 256;
    int mblocks = nchunks < 512 ? nchunks : 512;

    size_t pair_bytes = (size_t)NLEV * TSIZE * sizeof(uint2);   // 67.1 MB
    size_t feat_bytes = (size_t)NLEV * n * sizeof(__hip_bfloat162);

    if (ws_size >= pair_bytes + feat_bytes) {
        uint2* pair = (uint2*)d_ws;
        __hip_bfloat162* feat = (__hip_bfloat162*)((char*)d_ws + pair_bytes);
        int total = NLEV * (int)TSIZE;
        hipLaunchKernelGGL(convert_table_kernel, dim3(2048), dim3(256), 0, stream,
                           (const float2*)table, pair, total);
        hipLaunchKernelGGL(hash_encode_pair_kernel, dim3(16 * bpl), dim3(256), 0, stream,
                           pos, pair, feat, n, bpl);
        hipLaunchKernelGGL(mlp_mfma_kernel, dim3(mblocks), dim3(256), 0, stream,
                           pos, (const unsigned*)feat, W0, W1, W2, W3, out, n, nchunks);
    } else if (ws_size >= feat_bytes) {
        __hip_bfloat162* feat = (__hip_bfloat162*)d_ws;
        hipLaunchKernelGGL(hash_encode_kernel, dim3(16 * bpl), dim3(256), 0, stream,
                           pos, table, feat, n, bpl);
        hipLaunchKernelGGL(mlp_mfma_kernel, dim3(mblocks), dim3(256), 0, stream,
                           pos, (const unsigned*)feat, W0, W1, W2, W3, out, n, nchunks);
    } else {
        hipLaunchKernelGGL(hashgrid_fused_kernel, dim3(bpl), dim3(256), 0, stream,
                           pos, table, W0, W1, W2, W3, out, n);
    }
}